// Round 8
// baseline (430.662 us; speedup 1.0000x reference)
//
#include <hip/hip_runtime.h>
#include <hip/hip_fp16.h>
#include <hip/hip_cooperative_groups.h>
#include <stdint.h>

namespace cg = cooperative_groups;

typedef _Float16 half_t;
typedef __attribute__((ext_vector_type(8))) _Float16 half8;   // MFMA A/B frag (4 VGPRs)
typedef __attribute__((ext_vector_type(16))) float f32x16;    // 32x32 MFMA C/D frag
typedef __attribute__((ext_vector_type(4)))  float float4v;

#define BM 256
#define BN 256
#define BK 64     // 8 chunks of 8 halves (16 B) per row
#define NTHR 512  // 8 waves

#define VMCNT(n) asm volatile("s_waitcnt vmcnt(" #n ")" ::: "memory")

__device__ __forceinline__ void gld_lds16(const void* g, void* l) {
    __builtin_amdgcn_global_load_lds(
        (const __attribute__((address_space(1))) void*)g,
        (__attribute__((address_space(3))) void*)l, 16, 0, 0);
}

// ---------------------------------------------------------------------------
// R8: quantize-once returns, in the R2-proven-safe form (ONE cooperative
// dispatch; d_ws fully rewritten every call; no cross-dispatch d_ws window
// = R0's failure class stays eliminated).
//
// R7 post-mortem: fused kernel's structural tax per K-step = fp32 staging
// (2x bytes through L2/LLC, ~2340 cyc) + 16x redundant re-quantize of every
// panel element + ds_writes + cvt VALU. Scheduling was exhausted (R3-R7
// moved 304->221). Phase 1 quantizes x,w -> f16 in d_ws ONCE (fp32->f16 RNE
// == reference e5m10 quantize incl. denormals); grid.sync; phase 2 = R7's
// 256^2 8-wave GEMM but staging f16 via global_load_lds width=16 (no
// staging regs, no cvt, no ds_write in the K-loop; staged bytes halved).
// R2's failure cause (launch_bounds(256,4) -> VGPR 60 squeeze) avoided:
// (512,1), 1 block/CU, 256 blocks == cooperative capacity.
//
// LDS layout/swizzle carried over verbatim (rule #21 satisfied: linear LDS
// dest, inverse-swizzled global source kc=(c&7)^(row&7), swizzled read
// cp^sw). global_load_lds dest = wave-uniform base + lane*16 since chunk
// index c = t + 512*s is lane-consecutive.
// K-loop (T3-minimum): STAGE(buf[nxt], kt+1) -> 4 slices of
// {6 ds_read_b128 + 8 MFMA (setprio)} on buf[cur] -> barrier (drains DMA;
// loads had the whole MFMA phase in flight). One barrier per step; hazard
// audit: step t DMA-writes buf[nxt] whose readers finished before step
// t-1's barrier; step t+1's readers run after step t's barrier.
// ---------------------------------------------------------------------------
__global__ __launch_bounds__(512, 1)
void gemm_coop2(const float* __restrict__ x, const float* __restrict__ w,
                const float* __restrict__ bias, float* __restrict__ C,
                half_t* __restrict__ q, int M, int N, int K) {
    // ---------------- phase 1: quantize both tensors into q ----------------
    const long na   = (long)M * K;
    const long ntot = na + (long)N * K;
    {
        const long nchunk = ntot >> 3;
        const long nthrG  = (long)gridDim.x * blockDim.x;
        const long cid    = (long)blockIdx.x * blockDim.x + threadIdx.x;
        for (long c = cid; c < nchunk; c += nthrG) {
            const long i = c * 8;
            if (i < na && i + 8 > na) {              // straddle guard (generic)
                for (long j = i; j < i + 8; ++j)
                    q[j] = (half_t)(j < na ? x[j] : w[j - na]);
                continue;
            }
            const float* src = (i < na) ? (x + i) : (w + (i - na));
            float4v v0 = *(const float4v*)(src);
            float4v v1 = *(const float4v*)(src + 4);
            half8 h;
            h[0] = (half_t)v0[0]; h[1] = (half_t)v0[1];
            h[2] = (half_t)v0[2]; h[3] = (half_t)v0[3];
            h[4] = (half_t)v1[0]; h[5] = (half_t)v1[1];
            h[6] = (half_t)v1[2]; h[7] = (half_t)v1[3];
            *(half8*)(q + i) = h;
        }
        if (cid == 0)
            for (long i = nchunk * 8; i < ntot; ++i)
                q[i] = (half_t)(i < na ? x[i] : w[i - na]);
    }

    __threadfence();          // release q out of this XCD's L2
    cg::this_grid().sync();
    __threadfence();          // acquire: drop stale lines

    // ---------------- phase 2: GEMM on f16 panels --------------------------
    const half_t* A = q;           // [M][K]
    const half_t* B = q + na;      // [N][K]

    __shared__ half_t sA[2][BM * BK];   // 2 x 32 KB
    __shared__ half_t sB[2][BN * BK];   // 2 x 32 KB

    const int t    = threadIdx.x;
    const int lane = t & 63;
    const int wave = t >> 6;            // 0..7
    const int wm   = (wave >> 2) * 128; // {0,128}
    const int wn   = (wave & 3) * 64;   // {0,64,128,192}

    // XCD-aware 1-D -> 2-D block swizzle (specialized for the 16x16 grid)
    const int nbx = N / BN, nby = M / BM;
    int bxi, byi;
    {
        const int b = blockIdx.x;
        if (nbx == 16 && nby == 16) {
            const int xcd = b & 7;      // round-robin assumption, perf-only
            const int s   = b >> 3;     // 0..31
            bxi = xcd * 2 + (s & 1);    // 2-wide bn strip per XCD
            byi = s >> 1;
        } else {
            bxi = b % nbx;
            byi = b / nbx;
        }
    }
    const int bm = byi * BM;
    const int bn = bxi * BN;

    // staging: 2048 16B-chunks per matrix per K-step, 4 per thread;
    // chunk c: row = c>>3, LDS pos = c&7 (linear dest), global k-chunk =
    // (c&7) ^ (row&7) (inverse swizzle on the SOURCE address)
    const half_t* qa[4];
    const half_t* qb[4];
    int ldsoff[4];
    #pragma unroll
    for (int s = 0; s < 4; ++s) {
        const int c   = t + NTHR * s;
        const int row = c >> 3;
        const int kc  = (c & 7) ^ (row & 7);
        qa[s] = A + (long)(bm + row) * K + kc * 8;
        qb[s] = B + (long)(bn + row) * K + kc * 8;
        ldsoff[s] = c * 8;
    }

    f32x16 acc[4][2] = {};

    const int ml = lane & 31;   // m (or n) within 32-tile
    const int kg = lane >> 5;   // which 8-k half of the MFMA's K=16
    const int sw = ml & 7;      // row component of the XOR swizzle

    const int NT = K / BK;

    #define STAGE(buf)                                                         \
        do {                                                                   \
            _Pragma("unroll")                                                  \
            for (int s = 0; s < 4; ++s) {                                      \
                gld_lds16(qa[s], &sA[buf][ldsoff[s]]);                         \
                gld_lds16(qb[s], &sB[buf][ldsoff[s]]);                         \
                qa[s] += BK; qb[s] += BK;                                      \
            }                                                                  \
        } while (0)

    #define SLICE(ks)                                                          \
        do {                                                                   \
            const int cp = 2 * (ks) + kg;                                      \
            half8 a_[4], b_[2];                                                \
            _Pragma("unroll")                                                  \
            for (int i = 0; i < 4; ++i)                                        \
                a_[i] = *(const half8*)&sA[cur][((wm + 32*i + ml) * 8 + (cp ^ sw)) * 8]; \
            _Pragma("unroll")                                                  \
            for (int j = 0; j < 2; ++j)                                        \
                b_[j] = *(const half8*)&sB[cur][((wn + 32*j + ml) * 8 + (cp ^ sw)) * 8]; \
            __builtin_amdgcn_s_setprio(1);                                     \
            _Pragma("unroll")                                                  \
            for (int i = 0; i < 4; ++i)                                        \
                _Pragma("unroll")                                              \
                for (int j = 0; j < 2; ++j)                                    \
                    acc[i][j] = __builtin_amdgcn_mfma_f32_32x32x16_f16(a_[i], b_[j], acc[i][j], 0, 0, 0); \
            __builtin_amdgcn_s_setprio(0);                                     \
        } while (0)

    // prologue: stage tile 0 into buf 0
    STAGE(0);
    __syncthreads();   // drains the DMA (vmcnt 0) + publishes LDS

    int cur = 0;
    for (int kt = 0; kt < NT; ++kt) {
        const int nxt = cur ^ 1;
        if (kt + 1 < NT) STAGE(nxt);   // DMA for next tile in flight across MFMA
        SLICE(0); SLICE(1); SLICE(2); SLICE(3);
        __syncthreads();               // drains next-tile DMA, publishes buf[nxt]
        cur ^= 1;
    }

    // Epilogue. 32x32 C/D layout [m74/m101]: col = lane&31,
    // row = (reg&3) + 8*(reg>>2) + 4*(lane>>5)
    const int cl  = lane & 31;
    const int rbs = 4 * (lane >> 5);
    #pragma unroll
    for (int j = 0; j < 2; ++j) {
        const int col = bn + wn + j * 32 + cl;
        const float bq = (float)(half_t)bias[col];   // inline bias quantize
        #pragma unroll
        for (int i = 0; i < 4; ++i) {
            #pragma unroll
            for (int r = 0; r < 16; ++r) {
                const int row = bm + wm + i * 32 + (r & 3) + 8 * (r >> 2) + rbs;
                C[(long)row * N + col] = acc[i][j][r] + bq;
            }
        }
    }
    #undef STAGE
    #undef SLICE
}

// ---------------------------------------------------------------------------
// Fallback: R7 fused kernel, verified 334us bench / 221us dispatch. Used only
// if ws_size is insufficient or cooperative launch is rejected.
// ---------------------------------------------------------------------------
__global__ __launch_bounds__(512, 1)
void gemm_qf16_ph(const float* __restrict__ A, const float* __restrict__ B,
                  const float* __restrict__ bias, float* __restrict__ C,
                  int M, int N, int K) {
    __shared__ half_t sA[2][BM * BK];
    __shared__ half_t sB[2][BN * BK];

    const int t    = threadIdx.x;
    const int lane = t & 63;
    const int wave = t >> 6;
    const int wm   = (wave >> 2) * 128;
    const int wn   = (wave & 3) * 64;

    const int nbx = N / BN, nby = M / BM;
    int bxi, byi;
    {
        const int b = blockIdx.x;
        if (nbx == 16 && nby == 16) {
            const int xcd = b & 7;
            const int s   = b >> 3;
            bxi = xcd * 2 + (s & 1);
            byi = s >> 1;
        } else {
            bxi = b % nbx;
            byi = b / nbx;
        }
    }
    const int bm = byi * BM;
    const int bn = bxi * BN;

    const float* pa[4];
    const float* pb[4];
    int ldsoff[4];
    #pragma unroll
    for (int s = 0; s < 4; ++s) {
        const int c   = t + NTHR * s;
        const int row = c >> 3;
        const int kc  = (c & 7) ^ (row & 7);
        pa[s] = A + (long)(bm + row) * K + kc * 8;
        pb[s] = B + (long)(bn + row) * K + kc * 8;
        ldsoff[s] = c * 8;
    }

    f32x16 acc[4][2] = {};

    const int ml = lane & 31;
    const int kg = lane >> 5;
    const int sw = ml & 7;

    float4v ra0[4], ra1[4], rb0[4], rb1[4];

    const int NT = K / BK;

    #pragma unroll
    for (int s = 0; s < 4; ++s) {
        ra0[s] = *(const float4v*)(pa[s]);
        ra1[s] = *(const float4v*)(pa[s] + 4);
        rb0[s] = *(const float4v*)(pb[s]);
        rb1[s] = *(const float4v*)(pb[s] + 4);
        pa[s] += BK; pb[s] += BK;
    }
    #pragma unroll
    for (int s = 0; s < 4; ++s) {
        half8 ha, hb;
        ha[0]=(half_t)ra0[s][0]; ha[1]=(half_t)ra0[s][1]; ha[2]=(half_t)ra0[s][2]; ha[3]=(half_t)ra0[s][3];
        ha[4]=(half_t)ra1[s][0]; ha[5]=(half_t)ra1[s][1]; ha[6]=(half_t)ra1[s][2]; ha[7]=(half_t)ra1[s][3];
        hb[0]=(half_t)rb0[s][0]; hb[1]=(half_t)rb0[s][1]; hb[2]=(half_t)rb0[s][2]; hb[3]=(half_t)rb0[s][3];
        hb[4]=(half_t)rb1[s][0]; hb[5]=(half_t)rb1[s][1]; hb[6]=(half_t)rb1[s][2]; hb[7]=(half_t)rb1[s][3];
        *(half8*)&sA[0][ldsoff[s]] = ha;
        *(half8*)&sB[0][ldsoff[s]] = hb;
    }
    VMCNT(0);
    __syncthreads();

    #define SLICE_F(ks)                                                        \
        do {                                                                   \
            const int cp = 2 * (ks) + kg;                                      \
            half8 a_[4], b_[2];                                                \
            _Pragma("unroll")                                                  \
            for (int i = 0; i < 4; ++i)                                        \
                a_[i] = *(const half8*)&sA[cur][((wm + 32*i + ml) * 8 + (cp ^ sw)) * 8]; \
            _Pragma("unroll")                                                  \
            for (int j = 0; j < 2; ++j)                                        \
                b_[j] = *(const half8*)&sB[cur][((wn + 32*j + ml) * 8 + (cp ^ sw)) * 8]; \
            __builtin_amdgcn_s_setprio(1);                                     \
            _Pragma("unroll")                                                  \
            for (int i = 0; i < 4; ++i)                                        \
                _Pragma("unroll")                                              \
                for (int j = 0; j < 2; ++j)                                    \
                    acc[i][j] = __builtin_amdgcn_mfma_f32_32x32x16_f16(a_[i], b_[j], acc[i][j], 0, 0, 0); \
            __builtin_amdgcn_s_setprio(0);                                     \
        } while (0)

    #define CVTWR_F(g)                                                         \
        do {                                                                   \
            half8 ha, hb;                                                      \
            ha[0]=(half_t)ra0[g][0]; ha[1]=(half_t)ra0[g][1]; ha[2]=(half_t)ra0[g][2]; ha[3]=(half_t)ra0[g][3]; \
            ha[4]=(half_t)ra1[g][0]; ha[5]=(half_t)ra1[g][1]; ha[6]=(half_t)ra1[g][2]; ha[7]=(half_t)ra1[g][3]; \
            hb[0]=(half_t)rb0[g][0]; hb[1]=(half_t)rb0[g][1]; hb[2]=(half_t)rb0[g][2]; hb[3]=(half_t)rb0[g][3]; \
            hb[4]=(half_t)rb1[g][0]; hb[5]=(half_t)rb1[g][1]; hb[6]=(half_t)rb1[g][2]; hb[7]=(half_t)rb1[g][3]; \
            *(half8*)&sA[nxt][ldsoff[g]] = ha;                                 \
            *(half8*)&sB[nxt][ldsoff[g]] = hb;                                 \
        } while (0)

    int cur = 0;
    for (int kt = 0; kt < NT - 1; ++kt) {
        const int nxt = cur ^ 1;
        #pragma unroll
        for (int s = 0; s < 4; ++s) {
            asm volatile("global_load_dwordx4 %0, %2, off\n\t"
                         "global_load_dwordx4 %1, %2, off offset:16"
                         : "=&v"(ra0[s]), "=&v"(ra1[s])
                         : "v"(pa[s])
                         : "memory");
            asm volatile("global_load_dwordx4 %0, %2, off\n\t"
                         "global_load_dwordx4 %1, %2, off offset:16"
                         : "=&v"(rb0[s]), "=&v"(rb1[s])
                         : "v"(pb[s])
                         : "memory");
            pa[s] += BK; pb[s] += BK;
        }
        __builtin_amdgcn_sched_barrier(0);

        SLICE_F(0);
        VMCNT(12); __builtin_amdgcn_sched_barrier(0); CVTWR_F(0);
        SLICE_F(1);
        VMCNT(8);  __builtin_amdgcn_sched_barrier(0); CVTWR_F(1);
        SLICE_F(2);
        VMCNT(4);  __builtin_amdgcn_sched_barrier(0); CVTWR_F(2);
        SLICE_F(3);
        VMCNT(0);  __builtin_amdgcn_sched_barrier(0); CVTWR_F(3);

        __syncthreads();
        cur ^= 1;
    }

    SLICE_F(0); SLICE_F(1); SLICE_F(2); SLICE_F(3);

    const int cl  = lane & 31;
    const int rbs = 4 * (lane >> 5);
    #pragma unroll
    for (int j = 0; j < 2; ++j) {
        const int col = bn + wn + j * 32 + cl;
        const float bq = (float)(half_t)bias[col];
        #pragma unroll
        for (int i = 0; i < 4; ++i) {
            #pragma unroll
            for (int r = 0; r < 16; ++r) {
                const int row = bm + wm + i * 32 + (r & 3) + 8 * (r >> 2) + rbs;
                C[(long)row * N + col] = acc[i][j][r] + bq;
            }
        }
    }
    #undef SLICE_F
    #undef CVTWR_F
}

extern "C" void kernel_launch(void* const* d_in, const int* in_sizes, int n_in,
                              void* d_out, int out_size, void* d_ws, size_t ws_size,
                              hipStream_t stream) {
    const float* x    = (const float*)d_in[0];
    const float* w    = (const float*)d_in[1];
    const float* bias = (const float*)d_in[2];
    float* out = (float*)d_out;

    const int OUT = in_sizes[2];
    const int IN  = in_sizes[1] / OUT;
    const int M   = in_sizes[0] / IN;
    const int N   = OUT, K = IN;

    const int nblk = (N / BN) * (M / BM);
    const size_t needed = ((size_t)M * K + (size_t)N * K) * sizeof(half_t);

    if (ws_size >= needed && nblk <= 256) {
        half_t* q = (half_t*)d_ws;
        void* args[] = {(void*)&x, (void*)&w, (void*)&bias, (void*)&out,
                        (void*)&q, (void*)&M, (void*)&N, (void*)&K};
        hipError_t e = hipLaunchCooperativeKernel((const void*)gemm_coop2,
                                                  dim3(nblk), dim3(NTHR),
                                                  args, 0, stream);
        if (e == hipSuccess) return;
    }
    gemm_qf16_ph<<<nblk, NTHR, 0, stream>>>(x, w, bias, out, M, N, K);
    (void)n_in; (void)out_size;
}

// Round 9
// 334.794 us; speedup vs baseline: 1.2863x; 1.2863x over previous
//
#include <hip/hip_runtime.h>
#include <hip/hip_fp16.h>
#include <stdint.h>

typedef _Float16 half_t;
typedef __attribute__((ext_vector_type(8))) _Float16 half8;   // MFMA A/B frag (4 VGPRs)
typedef __attribute__((ext_vector_type(16))) float f32x16;    // 32x32 MFMA C/D frag
typedef __attribute__((ext_vector_type(4)))  float float4v;

#define BM 256
#define BN 256
#define BK 64     // 8 chunks of 8 halves (16 B) per row
#define NTHR 512  // 8 waves

#define VMCNT(n) asm volatile("s_waitcnt vmcnt(" #n ")" ::: "memory")

// Data-tied counted wait: the staging regs of group g are in-out operands,
// so their users (the cvts) chain THROUGH this asm and cannot hoist above
// the wait -- without a sched_barrier wall. Volatile-asm program order vs
// the (volatile) staging loads keeps the vmcnt count valid. ds_read/MFMA
// are untouched by this asm and remain free to schedule across it.
#define VMWAIT_TIE(n, g)                                                       \
    asm volatile("s_waitcnt vmcnt(" #n ")"                                     \
                 : "+v"(ra0[g]), "+v"(ra1[g]), "+v"(rb0[g]), "+v"(rb1[g]))

// ---------------------------------------------------------------------------
// R9: R7 fused kernel with the scheduling walls removed.
//
// Architecture verdict (R0/R2/R8): quantize-once designs pay ~+100us twice
// (coop R2: 437 vs 304; coop R8: 310 vs 221) and the two-dispatch form
// failed post-timing (R0). Fused quantize-on-stage is the architecture.
//
// R8->R9 theory: R7's LDS-pipe work (~109us: 192 ds_read_b128 + 64
// ds_write_b128 + conflicts per block-step) runs at ~50% utilization
// because the rule-#18 sched_barrier(0) after each VMCNT walls every
// slice: no cross-slice ds_read/MFMA overlap. Replace fence-ordering with
// DATA-dependency ordering (VMWAIT_TIE): cvts still can't hoist above
// their wait, but the scheduler may now pipeline slice s+1's ds_reads
// under slice s's MFMAs. One variable changed vs R7.
//
// K-step: issue 16 asm staging loads -> {SLICE(s); tied-wait; CVTWR(s)}
// x4 (vmcnt 12/8/4/0) -> barrier. One barrier per step; hazard audit
// unchanged (reads buf[cur], writes buf[cur^1], separated by the previous
// step's trailing barrier).
//
// quantize == fp32->f16 RNE cvt (reference e5m10 quantize incl. denormals)
// on stage for A/B, inline for bias.
// C[m][n] = sum_k qA[m][k]*qB[n][k] + q(bias[n]); mfma_f32_32x32x16_f16;
// 8 waves, 128x64 per wave (4x2 of 32x32); XOR k-chunk LDS swizzle
// (kc=(c&7)^(row&7) on the source, cp^sw on the read); XCD-aware block
// swizzle (2-wide bn strip per XCD, perf-only).
// ---------------------------------------------------------------------------
__global__ __launch_bounds__(512, 1)
void gemm_qf16_r9(const float* __restrict__ A, const float* __restrict__ B,
                  const float* __restrict__ bias, float* __restrict__ C,
                  int M, int N, int K) {
    __shared__ half_t sA[2][BM * BK];   // 2 x 32 KB
    __shared__ half_t sB[2][BN * BK];   // 2 x 32 KB

    const int t    = threadIdx.x;
    const int lane = t & 63;
    const int wave = t >> 6;            // 0..7
    const int wm   = (wave >> 2) * 128; // {0,128}
    const int wn   = (wave & 3) * 64;   // {0,64,128,192}

    // XCD-aware 1-D -> 2-D block swizzle (specialized for the 16x16 grid)
    const int nbx = N / BN, nby = M / BM;
    int bxi, byi;
    {
        const int b = blockIdx.x;
        if (nbx == 16 && nby == 16) {
            const int xcd = b & 7;      // round-robin assumption, perf-only
            const int s   = b >> 3;     // 0..31
            bxi = xcd * 2 + (s & 1);    // 2-wide bn strip per XCD
            byi = s >> 1;
        } else {
            bxi = b % nbx;
            byi = b / nbx;
        }
    }
    const int bm = byi * BM;
    const int bn = bxi * BN;

    // staging: 2048 16B-f16-chunks per matrix per K-step, 4 per thread;
    // chunk c: row = c>>3, LDS pos = c&7, global k-chunk = (c&7) ^ (row&7)
    const float* pa[4];
    const float* pb[4];
    int ldsoff[4];
    #pragma unroll
    for (int s = 0; s < 4; ++s) {
        const int c   = t + NTHR * s;
        const int row = c >> 3;
        const int kc  = (c & 7) ^ (row & 7);
        pa[s] = A + (long)(bm + row) * K + kc * 8;
        pb[s] = B + (long)(bn + row) * K + kc * 8;
        ldsoff[s] = c * 8;
    }

    f32x16 acc[4][2] = {};

    const int ml = lane & 31;   // m (or n) within 32-tile
    const int kg = lane >> 5;   // which 8-k half of the MFMA's K=16
    const int sw = ml & 7;      // row component of the XOR swizzle

    float4v ra0[4], ra1[4], rb0[4], rb1[4];

    const int NT = K / BK;

    // ---- prologue: synchronous load + cvt + write buf 0 ----
    #pragma unroll
    for (int s = 0; s < 4; ++s) {
        ra0[s] = *(const float4v*)(pa[s]);
        ra1[s] = *(const float4v*)(pa[s] + 4);
        rb0[s] = *(const float4v*)(pb[s]);
        rb1[s] = *(const float4v*)(pb[s] + 4);
        pa[s] += BK; pb[s] += BK;
    }
    #pragma unroll
    for (int s = 0; s < 4; ++s) {
        half8 ha, hb;
        ha[0]=(half_t)ra0[s][0]; ha[1]=(half_t)ra0[s][1]; ha[2]=(half_t)ra0[s][2]; ha[3]=(half_t)ra0[s][3];
        ha[4]=(half_t)ra1[s][0]; ha[5]=(half_t)ra1[s][1]; ha[6]=(half_t)ra1[s][2]; ha[7]=(half_t)ra1[s][3];
        hb[0]=(half_t)rb0[s][0]; hb[1]=(half_t)rb0[s][1]; hb[2]=(half_t)rb0[s][2]; hb[3]=(half_t)rb0[s][3];
        hb[4]=(half_t)rb1[s][0]; hb[5]=(half_t)rb1[s][1]; hb[6]=(half_t)rb1[s][2]; hb[7]=(half_t)rb1[s][3];
        *(half8*)&sA[0][ldsoff[s]] = ha;
        *(half8*)&sB[0][ldsoff[s]] = hb;
    }
    VMCNT(0);          // normalize the counter before the counted-wait loop
    __syncthreads();

    #define SLICE(ks)                                                          \
        do {                                                                   \
            const int cp = 2 * (ks) + kg;                                      \
            half8 a_[4], b_[2];                                                \
            _Pragma("unroll")                                                  \
            for (int i = 0; i < 4; ++i)                                        \
                a_[i] = *(const half8*)&sA[cur][((wm + 32*i + ml) * 8 + (cp ^ sw)) * 8]; \
            _Pragma("unroll")                                                  \
            for (int j = 0; j < 2; ++j)                                        \
                b_[j] = *(const half8*)&sB[cur][((wn + 32*j + ml) * 8 + (cp ^ sw)) * 8]; \
            __builtin_amdgcn_s_setprio(1);                                     \
            _Pragma("unroll")                                                  \
            for (int i = 0; i < 4; ++i)                                        \
                _Pragma("unroll")                                              \
                for (int j = 0; j < 2; ++j)                                    \
                    acc[i][j] = __builtin_amdgcn_mfma_f32_32x32x16_f16(a_[i], b_[j], acc[i][j], 0, 0, 0); \
            __builtin_amdgcn_s_setprio(0);                                     \
        } while (0)

    #define CVTWR(g)                                                           \
        do {                                                                   \
            half8 ha, hb;                                                      \
            ha[0]=(half_t)ra0[g][0]; ha[1]=(half_t)ra0[g][1]; ha[2]=(half_t)ra0[g][2]; ha[3]=(half_t)ra0[g][3]; \
            ha[4]=(half_t)ra1[g][0]; ha[5]=(half_t)ra1[g][1]; ha[6]=(half_t)ra1[g][2]; ha[7]=(half_t)ra1[g][3]; \
            hb[0]=(half_t)rb0[g][0]; hb[1]=(half_t)rb0[g][1]; hb[2]=(half_t)rb0[g][2]; hb[3]=(half_t)rb0[g][3]; \
            hb[4]=(half_t)rb1[g][0]; hb[5]=(half_t)rb1[g][1]; hb[6]=(half_t)rb1[g][2]; hb[7]=(half_t)rb1[g][3]; \
            *(half8*)&sA[nxt][ldsoff[g]] = ha;                                 \
            *(half8*)&sB[nxt][ldsoff[g]] = hb;                                 \
        } while (0)

    int cur = 0;
    for (int kt = 0; kt < NT - 1; ++kt) {
        const int nxt = cur ^ 1;

        // issue next tile's 16 staging loads (4 groups x [2xA, 2xB] dwordx4);
        // group g occupies vm-queue slots 4g..4g+3
        #pragma unroll
        for (int s = 0; s < 4; ++s) {
            asm volatile("global_load_dwordx4 %0, %2, off\n\t"
                         "global_load_dwordx4 %1, %2, off offset:16"
                         : "=&v"(ra0[s]), "=&v"(ra1[s])
                         : "v"(pa[s])
                         : "memory");
            asm volatile("global_load_dwordx4 %0, %2, off\n\t"
                         "global_load_dwordx4 %1, %2, off offset:16"
                         : "=&v"(rb0[s]), "=&v"(rb1[s])
                         : "v"(pb[s])
                         : "memory");
            pa[s] += BK; pb[s] += BK;
        }

        SLICE(0);
        VMWAIT_TIE(12, 0); CVTWR(0);
        SLICE(1);
        VMWAIT_TIE(8, 1);  CVTWR(1);
        SLICE(2);
        VMWAIT_TIE(4, 2);  CVTWR(2);
        SLICE(3);
        VMWAIT_TIE(0, 3);  CVTWR(3);

        __syncthreads();
        cur ^= 1;
    }

    // ---- final tile: MFMA only ----
    SLICE(0); SLICE(1); SLICE(2); SLICE(3);

    // Epilogue. 32x32 C/D layout [m74/m101]: col = lane&31,
    // row = (reg&3) + 8*(reg>>2) + 4*(lane>>5)
    const int cl  = lane & 31;
    const int rbs = 4 * (lane >> 5);
    #pragma unroll
    for (int j = 0; j < 2; ++j) {
        const int col = bn + wn + j * 32 + cl;
        const float bq = (float)(half_t)bias[col];   // inline bias quantize
        #pragma unroll
        for (int i = 0; i < 4; ++i) {
            #pragma unroll
            for (int r = 0; r < 16; ++r) {
                const int row = bm + wm + i * 32 + (r & 3) + 8 * (r >> 2) + rbs;
                C[(long)row * N + col] = acc[i][j][r] + bq;
            }
        }
    }
    #undef SLICE
    #undef CVTWR
}

extern "C" void kernel_launch(void* const* d_in, const int* in_sizes, int n_in,
                              void* d_out, int out_size, void* d_ws, size_t ws_size,
                              hipStream_t stream) {
    const float* x    = (const float*)d_in[0];
    const float* w    = (const float*)d_in[1];
    const float* bias = (const float*)d_in[2];
    float* out = (float*)d_out;

    const int OUT = in_sizes[2];
    const int IN  = in_sizes[1] / OUT;
    const int M   = in_sizes[0] / IN;
    const int N   = OUT, K = IN;

    dim3 grid((N / BN) * (M / BM));
    gemm_qf16_r9<<<grid, NTHR, 0, stream>>>(x, w, bias, out, M, N, K);
    (void)d_ws; (void)ws_size; (void)n_in; (void)out_size;
}